// Round 3
// 3362.055 us; speedup vs baseline: 1.0193x; 1.0193x over previous
//
#include <hip/hip_runtime.h>
#include <stdint.h>
#include <stddef.h>

#define VOCAB 32000
#define HID   1024
#define BATCH 256
#define SEQ   512
#define G3    3072

// gru partitioning: 8 independent groups (heuristically one per XCD via bid&7),
// each group = 32 WGs x (32 batch rows, full 3072 gate cols; 32 hidden cols/WG)
// This round vs the proven 3427us baseline: per-WAVE dataflow flags published
// right after the wave's own h-store ack (s_waitcnt vmcnt(0)), instead of a
// WG-wide tid0 flag after __syncthreads. Removes barrier-join + slowest-sibling
// store-ack from the inter-WG critical path. All memory primitives unchanged.
#define GRP   8
#define GWG   32
#define MROWS 32
#define PW    100   // pbuf row stride (floats): 96 cols + 4 pad
#define CR    40    // staged-chunk row stride (bf16 elems): 32 + 8 pad (80 B, 16B-aligned)

typedef unsigned short u16;
typedef unsigned long long u64;
typedef short bf16x8 __attribute__((ext_vector_type(8)));
typedef float f32x4 __attribute__((ext_vector_type(4)));
typedef u16   u16x4 __attribute__((ext_vector_type(4)));

typedef void __attribute__((address_space(1))) gvoid;
typedef void __attribute__((address_space(3))) lvoid;

__device__ __forceinline__ u16 f2b(float f) {
  union { float f; unsigned u; } x; x.f = f;
  return (u16)((x.u + 0x7fffu + ((x.u >> 16) & 1u)) >> 16);
}
__device__ __forceinline__ float b2f(u16 u) {
  union { unsigned u; float f; } x; x.u = ((unsigned)u) << 16;
  return x.f;
}
__device__ __forceinline__ float sigmf(float x) { return 1.0f / (1.0f + __expf(-x)); }
__device__ __forceinline__ float tanhft(float x) { return 1.0f - 2.0f / (__expf(2.0f * x) + 1.0f); }

__device__ __forceinline__ void glds16(const void* g, void* l) {
  __builtin_amdgcn_global_load_lds((gvoid*)g, (lvoid*)l, 16, 0, 0);
}

// cache-bypass (agent-scope relaxed atomic) 8B load/store — no fences anywhere
__device__ __forceinline__ u64 ld_byp(const u16* p) {
  return __hip_atomic_load((const u64*)p, __ATOMIC_RELAXED, __HIP_MEMORY_SCOPE_AGENT);
}
__device__ __forceinline__ void st_byp(u16* p, u64 v) {
  __hip_atomic_store((u64*)p, v, __ATOMIC_RELAXED, __HIP_MEMORY_SCOPE_AGENT);
}
union B4U { u16x4 s; u64 u; };

// ---------------- Phase A0: fp32 -> bf16 conversion ----------------
__global__ __launch_bounds__(256) void cvt_kernel(const float* __restrict__ s,
                                                  u16* __restrict__ d, int n) {
  const int i = (blockIdx.x * 256 + threadIdx.x) * 4;
  if (i + 3 < n) {
    const f32x4 v = *(const f32x4*)(s + i);
    u16x4 o;
    o.x = f2b(v.x); o.y = f2b(v.y); o.z = f2b(v.z); o.w = f2b(v.w);
    *(u16x4*)(d + i) = o;
  }
}

// ---------------- Phase A1: emb_proj = emb_b @ Wih_b^T + b_ih (bf16 out) ----------------
__global__ __launch_bounds__(256) void embproj_gemm(const u16* __restrict__ A,
                                                    const u16* __restrict__ Bm,
                                                    const float* __restrict__ bias,
                                                    u16* __restrict__ C) {
  __shared__ u16 sA[128 * 32];
  __shared__ u16 sB[128 * 32];
  const int tid = threadIdx.x;
  const int w = tid >> 6, l = tid & 63;
  const int wm = w >> 1, wn = w & 1;
  const int m0 = (int)(blockIdx.x / 24) * 128;
  const int n0 = (int)(blockIdx.x % 24) * 128;
  const int row1 = tid >> 2;
  const int kh1  = tid & 3;
  const int kin  = (l >> 4) << 3;
  const int lm   = l & 15;

  f32x4 acc[4][4] = {};
  char* sAb = (char*)sA;
  char* sBb = (char*)sB;

  for (int k0 = 0; k0 < HID; k0 += 32) {
    __syncthreads();
    glds16(A + (size_t)(m0 + row1) * HID + k0 + kh1 * 8,       sAb + w * 1024);
    glds16(A + (size_t)(m0 + 64 + row1) * HID + k0 + kh1 * 8,  sAb + 4096 + w * 1024);
    glds16(Bm + (size_t)(n0 + row1) * HID + k0 + kh1 * 8,      sBb + w * 1024);
    glds16(Bm + (size_t)(n0 + 64 + row1) * HID + k0 + kh1 * 8, sBb + 4096 + w * 1024);
    __syncthreads();
    bf16x8 aF[4], bF[4];
#pragma unroll
    for (int mt = 0; mt < 4; ++mt)
      aF[mt] = *(const bf16x8*)&sA[(64 * wm + 16 * mt + lm) * 32 + kin];
#pragma unroll
    for (int nt = 0; nt < 4; ++nt)
      bF[nt] = *(const bf16x8*)&sB[(64 * wn + 16 * nt + lm) * 32 + kin];
#pragma unroll
    for (int mt = 0; mt < 4; ++mt)
#pragma unroll
      for (int nt = 0; nt < 4; ++nt)
        acc[mt][nt] = __builtin_amdgcn_mfma_f32_16x16x32_bf16(aF[mt], bF[nt], acc[mt][nt], 0, 0, 0);
  }
  __syncthreads();
#pragma unroll
  for (int mt = 0; mt < 4; ++mt)
#pragma unroll
    for (int nt = 0; nt < 4; ++nt) {
      const int col = n0 + 64 * wn + 16 * nt + lm;
      const float bi = bias[col];
      const int rbase = m0 + 64 * wm + 16 * mt + ((l >> 4) << 2);
#pragma unroll
      for (int i = 0; i < 4; ++i)
        C[(size_t)(rbase + i) * G3 + col] = f2b(acc[mt][nt][i] + bi);
    }
}

// ---------------- Phase B: persistent GRU, per-WAVE dataflow flags ----------------
__global__ __launch_bounds__(256, 1) void gru_persist(
    const int* __restrict__ inputs, const float* __restrict__ Whh,
    const float* __restrict__ bhh, const u16* __restrict__ embproj,
    const float* __restrict__ Wd, const float* __restrict__ bd,
    u16* __restrict__ hAb, u16* __restrict__ hBb,
    unsigned* __restrict__ flags, float* __restrict__ out) {
  extern __shared__ char smem[];
  u16* sH = (u16*)smem;                         // 4 waves x 8 chunks x 32 rows x CR = 81920 B
  float* pbuf = (float*)(smem + 4 * 8 * 32 * CR * 2);  // [4][32][PW] = 51200 B
  float* cred = pbuf + 4 * MROWS * PW;          // [16]

  const int tid = threadIdx.x;
  const int w = tid >> 6, l = tid & 63;
  const int lm = l & 15, kin = (l >> 4) << 3;
  const int bid = blockIdx.x;
  const int g  = bid & 7;    // group (heuristic: XCD id)
  const int ig = bid >> 3;   // 0..31 within group
  const int m0 = g * MROWS;
  const int j0 = ig * 32;    // 32 hidden cols per WG -> 96 gate cols
  unsigned* gflags = flags + g * 128;  // per-wave flags: index (ig<<2)+w, 128/group

  // ---- preload W_hh fragments into registers: 6 col-frags x 8 kk (192 VGPRs) ----
  const int kb = w << 8;  // 256-wide K slice per wave
  bf16x8 wf[6][8];
#pragma unroll
  for (int gg = 0; gg < 6; ++gg) {
    const int gate = gg >> 1;
    const size_t wrow = (size_t)(gate * HID + j0 + ((gg & 1) << 4) + lm) * HID;
#pragma unroll
    for (int kk = 0; kk < 8; ++kk) {
      const float* p = Whh + wrow + kb + (kk << 5) + kin;
      const f32x4 v0 = *(const f32x4*)p;
      const f32x4 v1 = *(const f32x4*)(p + 4);
      bf16x8 f;
      f[0] = (short)f2b(v0.x); f[1] = (short)f2b(v0.y);
      f[2] = (short)f2b(v0.z); f[3] = (short)f2b(v0.w);
      f[4] = (short)f2b(v1.x); f[5] = (short)f2b(v1.y);
      f[6] = (short)f2b(v1.z); f[7] = (short)f2b(v1.w);
      wf[gg][kk] = f;
    }
  }

  // ---- staging geometry (loop-invariant) ----
  u16* sHw = sH + w * (8 * 32 * CR);           // wave-private staging region
  const int srow = l >> 3;                      // 0..7 (global row within 8-row block)
  const int scol = (l & 7) << 2;                // 0,4,..,28 (elem col within 32-chunk)

  // ---- elementwise-phase constants: wave w owns rows [8w, 8w+8) ----
  const int er = tid >> 3;         // row 0..31 (== 8w + (l>>3))
  const int ec = (tid & 7) << 2;   // col 0,4,..,28 within 32-col slice
  const int b  = m0 + er;
  const f32x4 brv = *(const f32x4*)(bhh + j0 + ec);
  const f32x4 bzv = *(const f32x4*)(bhh + HID + j0 + ec);
  const f32x4 bnv = *(const f32x4*)(bhh + 2 * HID + j0 + ec);
  unsigned* myflag = gflags + (ig << 2) + w;

  f32x4 hreg = {0.f, 0.f, 0.f, 0.f};  // this thread's 4 fp32 h cells (h0 = 0)

  for (int t = 0; t < SEQ; ++t) {
    const u16* hcb = (t & 1) ? hBb : hAb;
    u16*       hnb = (t & 1) ? hAb : hBb;

    // prefetch gathers for this step (independent of h / flags)
    const int tok = inputs[b * SEQ + t];
    const u16x4 xr4 = *(const u16x4*)(embproj + (size_t)tok * G3 + j0 + ec);
    const u16x4 xz4 = *(const u16x4*)(embproj + (size_t)tok * G3 + HID + j0 + ec);
    const u16x4 xn4 = *(const u16x4*)(embproj + (size_t)tok * G3 + 2 * HID + j0 + ec);

    // ---- per-wave poll: the 32 producer WAVES (8 WGs x 4 waves) of this K slice ----
    // flags index (ig'<<2)+w' for ig' in [8w, 8w+8) == [32w, 32w+32); 2 lanes/flag
    if (t) {
      const unsigned want = (unsigned)t;
      for (;;) {
        const unsigned v = __hip_atomic_load(gflags + (w << 5) + ((l >> 1) & 31),
                                             __ATOMIC_RELAXED, __HIP_MEMORY_SCOPE_AGENT);
        if (__all(v >= want)) break;
        __builtin_amdgcn_s_sleep(1);
      }
    }

    // ---- coalesced staging: 32 rows x 256 cols (this wave's K slice) -> LDS ----
    u64 stg[8][4];
#pragma unroll
    for (int j = 0; j < 8; ++j)
#pragma unroll
      for (int q = 0; q < 4; ++q)
        stg[j][q] = ld_byp(hcb + (size_t)(m0 + (q << 3) + srow) * HID + kb + (j << 5) + scol);
#pragma unroll
    for (int j = 0; j < 8; ++j)
#pragma unroll
      for (int q = 0; q < 4; ++q)
        *(u64*)&sHw[((j << 5) + (q << 3) + srow) * CR + scol] = stg[j][q];

    // ---- MFMA: 2 m-tiles x 6 gate-frags x 8 K-chunks ----
    f32x4 acc[2][6] = {};
#pragma unroll
    for (int kk = 0; kk < 8; ++kk) {
      const bf16x8 a0 = *(const bf16x8*)&sHw[((kk << 5) + lm) * CR + kin];
      const bf16x8 a1 = *(const bf16x8*)&sHw[((kk << 5) + 16 + lm) * CR + kin];
#pragma unroll
      for (int gg = 0; gg < 6; ++gg) {
        acc[0][gg] = __builtin_amdgcn_mfma_f32_16x16x32_bf16(a0, wf[gg][kk], acc[0][gg], 0, 0, 0);
        acc[1][gg] = __builtin_amdgcn_mfma_f32_16x16x32_bf16(a1, wf[gg][kk], acc[1][gg], 0, 0, 0);
      }
    }

    // partials -> LDS (C layout: col=lane&15, row=(lane>>4)*4+i)
#pragma unroll
    for (int m = 0; m < 2; ++m)
#pragma unroll
      for (int gg = 0; gg < 6; ++gg) {
        const int rl = (m << 4) + ((l >> 4) << 2);
        const int cl = ((gg >> 1) << 5) + ((gg & 1) << 4) + lm;
#pragma unroll
        for (int i = 0; i < 4; ++i)
          pbuf[(w * MROWS + rl + i) * PW + cl] = acc[m][gg][i];
      }
    __syncthreads();  // SYNC1: pbuf ready; also joins all 4 waves' polls (union
                      // covers all 32 WGs >= t) before any h store -> WAR-safe

    // cross-wave reduce + gates (wave w: rows [8w,8w+8) x 32 cols, 4 cells/thread)
    f32x4 hr = brv, hz = bzv, hn = bnv;
#pragma unroll
    for (int ww = 0; ww < 4; ++ww) {
      const float* pp = &pbuf[(ww * MROWS + er) * PW];
      hr += *(const f32x4*)(pp + ec);
      hz += *(const f32x4*)(pp + 32 + ec);
      hn += *(const f32x4*)(pp + 64 + ec);
    }
    f32x4 hv; B4U hbu;
#pragma unroll
    for (int i = 0; i < 4; ++i) {
      const float r = sigmf(b2f(xr4[i]) + hr[i]);
      const float z = sigmf(b2f(xz4[i]) + hz[i]);
      const float n = tanhft(b2f(xn4[i]) + r * hn[i]);
      const float v2 = (1.0f - z) * n + z * hreg[i];
      hv[i] = v2; hbu.s[i] = f2b(v2);
    }
    hreg = hv;                                          // fp32 h stays in registers
    st_byp(hnb + (size_t)b * HID + j0 + ec, hbu.u);     // shared bf16: write-through

    // ---- per-wave publish: own store ack'd, then flag -- no barrier in between ----
    asm volatile("s_waitcnt vmcnt(0)" ::: "memory");
    if (l == 0)
      __hip_atomic_store(myflag, (unsigned)(t + 1), __ATOMIC_RELAXED,
                         __HIP_MEMORY_SCOPE_AGENT);
    __syncthreads();  // SYNC2: pbuf reuse safety only (off inter-WG critical path)
  }

  // ---- wait for whole group (all 128 wave-flags), then fused final dense ----
  {
    for (;;) {
      const unsigned v0 = __hip_atomic_load(gflags + l, __ATOMIC_RELAXED,
                                            __HIP_MEMORY_SCOPE_AGENT);
      const unsigned v1 = __hip_atomic_load(gflags + 64 + l, __ATOMIC_RELAXED,
                                            __HIP_MEMORY_SCOPE_AGENT);
      if (__all((v0 >= (unsigned)SEQ) && (v1 >= (unsigned)SEQ))) break;
      __builtin_amdgcn_s_sleep(1);
    }
    const int br = m0 + ig;
    const int k = tid << 2;
    B4U hw; hw.u = ld_byp(hAb + (size_t)br * HID + k);  // t=511 wrote hAb
    const f32x4 w0 = *(const f32x4*)(Wd + k);
    const f32x4 w1 = *(const f32x4*)(Wd + HID + k);
    float p0 = 0.f, p1 = 0.f;
#pragma unroll
    for (int i = 0; i < 4; ++i) {
      const float hvv = b2f(hw.s[i]);
      p0 += hvv * ((const float*)&w0)[i];
      p1 += hvv * ((const float*)&w1)[i];
    }
#pragma unroll
    for (int off = 32; off > 0; off >>= 1) {
      p0 += __shfl_down(p0, off);
      p1 += __shfl_down(p1, off);
    }
    if (l == 0) { cred[w] = p0; cred[8 + w] = p1; }
    __syncthreads();
    if (tid == 0) out[2 * br]     = cred[0] + cred[1] + cred[2] + cred[3] + bd[0];
    if (tid == 1) out[2 * br + 1] = cred[8] + cred[9] + cred[10] + cred[11] + bd[1];
  }
}

// ---------------- host launch ----------------
extern "C" void kernel_launch(void* const* d_in, const int* in_sizes, int n_in,
                              void* d_out, int out_size, void* d_ws, size_t ws_size,
                              hipStream_t stream) {
  const int*   inputs = (const int*)d_in[0];
  const float* emb = (const float*)d_in[1];
  const float* Wih = (const float*)d_in[2];
  const float* Whh = (const float*)d_in[3];
  const float* bih = (const float*)d_in[4];
  const float* bhh = (const float*)d_in[5];
  const float* Wd  = (const float*)d_in[6];
  const float* bd  = (const float*)d_in[7];

  char* ws = (char*)d_ws;
  unsigned* flags = (unsigned*)ws;                                  // [0, 4KB): 8 groups x 128 wave-flags
  u16* hAb = (u16*)(ws + (size_t)(1 << 20));                        // 512 KB
  u16* hBb = (u16*)(ws + (size_t)(1 << 20) + (size_t)(1 << 19));    // 512 KB
  u16* embproj = (u16*)(ws + (size_t)(2 << 20));                    // 196,608,000 B
  u16* embb = (u16*)(ws + 2097152ull + 196608000ull);               // 65,536,000 B
  u16* Wihb = (u16*)(ws + 2097152ull + 196608000ull + 65536000ull); // 6,291,456 B

  // zero flags + h bf16 double buffers (h0 = 0; flags must start 0 every launch)
  hipMemsetAsync(d_ws, 0, (size_t)(2 << 20), stream);

  cvt_kernel<<<32000, 256, 0, stream>>>(emb, embb, VOCAB * HID);
  cvt_kernel<<<3072, 256, 0, stream>>>(Wih, Wihb, G3 * HID);
  embproj_gemm<<<250 * 24, 256, 0, stream>>>(embb, Wihb, bih, embproj);

  const int smem_bytes = 4 * 8 * 32 * CR * 2 + 4 * MROWS * PW * 4 + 64;  // 133,248 B
  (void)hipFuncSetAttribute((const void*)gru_persist,
                            hipFuncAttributeMaxDynamicSharedMemorySize, smem_bytes);
  gru_persist<<<GRP * GWG, 256, smem_bytes, stream>>>(inputs, Whh, bhh, embproj, Wd, bd,
                                                      hAb, hBb, flags, (float*)d_out);
}